// Round 14
// baseline (136.164 us; speedup 1.0000x reference)
//
#include <hip/hip_runtime.h>
#include <math.h>

#define TPB 256

constexpr int Bn    = 131072;
constexpr float LOG2E = 1.4426950408889634f;

typedef float v2f __attribute__((ext_vector_type(2)));

__global__ __launch_bounds__(TPB)
void gat_ppo_kernel(const float* __restrict__ xg,
                    const float* __restrict__ adjg,
                    const float* __restrict__ Wg,
                    const float* __restrict__ ahg,
                    const float* __restrict__ wog,
                    const float* __restrict__ aog,
                    const float* __restrict__ muWg,
                    const float* __restrict__ mubg,
                    const float* __restrict__ sgWg,
                    const float* __restrict__ sgbg,
                    const float* __restrict__ vWg,
                    const float* __restrict__ vbg,
                    float* __restrict__ outg)
{
    // ONE THREAD = ONE GRAPH (N=8). Everything in registers: zero LDS,
    // zero shuffles, zero barriers. Head loop is a runtime loop (I-cache);
    // row/attention loops fully unrolled (static register indexing).
    const size_t b = (size_t)blockIdx.x * TPB + threadIdx.x;   // graph id

    // ---- adjacency 8x8 -> 64-bit mask ----
    unsigned long long am = 0ull;
    {
        const float4* a4 = (const float4*)(adjg + b * 64);
        #pragma unroll
        for (int i = 0; i < 16; ++i) {
            float4 v = a4[i];
            am |= ((unsigned long long)(v.x > 0.0f)) << (4 * i + 0);
            am |= ((unsigned long long)(v.y > 0.0f)) << (4 * i + 1);
            am |= ((unsigned long long)(v.z > 0.0f)) << (4 * i + 2);
            am |= ((unsigned long long)(v.w > 0.0f)) << (4 * i + 3);
        }
    }

    const v2f* Wp  = (const v2f*)Wg;
    const float* xb = xg + b * (8 * 30);

    float wh2[8];
    #pragma unroll
    for (int n = 0; n < 8; ++n) wh2[n] = 0.0f;

    #pragma unroll 1                       // runtime head loop: keep code small
    for (int h = 0; h < 3; ++h) {
        const v2f*   Whp = Wp + h * 120;
        const float* ah1 = ahg + h * 16;
        const float* ah2 = ahg + h * 16 + 8;
        const float* woh = wog + h * 8;

        v2f   wh[8][4];                    // full 8x8 Wh tile in registers
        float f1[8], f2[8];

        // ---- Wh rows: 8 x (load 30 floats, 120 pk-FMA, scores) ----
        #pragma unroll
        for (int n = 0; n < 8; ++n) {
            const float4* x4 = (const float4*)(xb + n * 30);
            float4 c0 = x4[0], c1 = x4[1], c2 = x4[2], c3 = x4[3];
            float4 c4 = x4[4], c5 = x4[5], c6 = x4[6];
            float2 c7 = ((const float2*)(xb + n * 30))[14];
            const float xv[30] = {c0.x,c0.y,c0.z,c0.w, c1.x,c1.y,c1.z,c1.w,
                                  c2.x,c2.y,c2.z,c2.w, c3.x,c3.y,c3.z,c3.w,
                                  c4.x,c4.y,c4.z,c4.w, c5.x,c5.y,c5.z,c5.w,
                                  c6.x,c6.y,c6.z,c6.w, c7.x,c7.y};
            v2f acc0 = (v2f){0.0f,0.0f}, acc1 = (v2f){0.0f,0.0f};
            v2f acc2 = (v2f){0.0f,0.0f}, acc3 = (v2f){0.0f,0.0f};
            #pragma unroll
            for (int f = 0; f < 30; ++f) {
                v2f xf = (v2f){xv[f], xv[f]};
                acc0 = __builtin_elementwise_fma(xf, Whp[f * 4 + 0], acc0);
                acc1 = __builtin_elementwise_fma(xf, Whp[f * 4 + 1], acc1);
                acc2 = __builtin_elementwise_fma(xf, Whp[f * 4 + 2], acc2);
                acc3 = __builtin_elementwise_fma(xf, Whp[f * 4 + 3], acc3);
            }
            wh[n][0] = acc0; wh[n][1] = acc1; wh[n][2] = acc2; wh[n][3] = acc3;

            float s1 = 0.0f, s2 = 0.0f;
            s1 = fmaf(acc0.x, ah1[0], s1); s1 = fmaf(acc0.y, ah1[1], s1);
            s1 = fmaf(acc1.x, ah1[2], s1); s1 = fmaf(acc1.y, ah1[3], s1);
            s1 = fmaf(acc2.x, ah1[4], s1); s1 = fmaf(acc2.y, ah1[5], s1);
            s1 = fmaf(acc3.x, ah1[6], s1); s1 = fmaf(acc3.y, ah1[7], s1);
            s2 = fmaf(acc0.x, ah2[0], s2); s2 = fmaf(acc0.y, ah2[1], s2);
            s2 = fmaf(acc1.x, ah2[2], s2); s2 = fmaf(acc1.y, ah2[3], s2);
            s2 = fmaf(acc2.x, ah2[4], s2); s2 = fmaf(acc2.y, ah2[5], s2);
            s2 = fmaf(acc3.x, ah2[6], s2); s2 = fmaf(acc3.y, ah2[7], s2);
            f1[n] = s1 * LOG2E;
            f2[n] = s2 * LOG2E;
        }

        // ---- attention per row, fully in-register (no cross-lane) ----
        #pragma unroll
        for (int n = 0; n < 8; ++n) {
            float s = 0.0f;
            v2f hacc0 = (v2f){0.0f,0.0f}, hacc1 = (v2f){0.0f,0.0f};
            v2f hacc2 = (v2f){0.0f,0.0f}, hacc3 = (v2f){0.0f,0.0f};
            #pragma unroll
            for (int m = 0; m < 8; ++m) {
                float ev = f1[n] + f2[m];
                ev = fmaxf(ev, 0.2f * ev);                 // leaky (log2-scaled)
                float pe = ((am >> (n * 8 + m)) & 1ull)
                         ? __builtin_amdgcn_exp2f(ev) : 0.0f;
                s += pe;
                v2f av = (v2f){pe, pe};
                hacc0 = __builtin_elementwise_fma(av, wh[m][0], hacc0);
                hacc1 = __builtin_elementwise_fma(av, wh[m][1], hacc1);
                hacc2 = __builtin_elementwise_fma(av, wh[m][2], hacc2);
                hacc3 = __builtin_elementwise_fma(av, wh[m][3], hacc3);
            }
            float rs = 1.0f / s;
            float hv;
            hv = hacc0.x * rs; hv = (hv > 0.0f) ? hv : (__expf(hv) - 1.0f); wh2[n] = fmaf(hv, woh[0], wh2[n]);
            hv = hacc0.y * rs; hv = (hv > 0.0f) ? hv : (__expf(hv) - 1.0f); wh2[n] = fmaf(hv, woh[1], wh2[n]);
            hv = hacc1.x * rs; hv = (hv > 0.0f) ? hv : (__expf(hv) - 1.0f); wh2[n] = fmaf(hv, woh[2], wh2[n]);
            hv = hacc1.y * rs; hv = (hv > 0.0f) ? hv : (__expf(hv) - 1.0f); wh2[n] = fmaf(hv, woh[3], wh2[n]);
            hv = hacc2.x * rs; hv = (hv > 0.0f) ? hv : (__expf(hv) - 1.0f); wh2[n] = fmaf(hv, woh[4], wh2[n]);
            hv = hacc2.y * rs; hv = (hv > 0.0f) ? hv : (__expf(hv) - 1.0f); wh2[n] = fmaf(hv, woh[5], wh2[n]);
            hv = hacc3.x * rs; hv = (hv > 0.0f) ? hv : (__expf(hv) - 1.0f); wh2[n] = fmaf(hv, woh[6], wh2[n]);
            hv = hacc3.y * rs; hv = (hv > 0.0f) ? hv : (__expf(hv) - 1.0f); wh2[n] = fmaf(hv, woh[7], wh2[n]);
        }
    }

    // ---- second GAT layer, fully in-register ----
    const float a0c = aog[0] * LOG2E, a1c = aog[1] * LOG2E;
    float g[8];
    #pragma unroll
    for (int n = 0; n < 8; ++n) {
        float g1 = a0c * wh2[n];
        float s2s = 0.0f, og = 0.0f;
        #pragma unroll
        for (int m = 0; m < 8; ++m) {
            float ev = fmaf(a1c, wh2[m], g1);
            ev = fmaxf(ev, 0.2f * ev);
            float pe = ((am >> (n * 8 + m)) & 1ull)
                     ? __builtin_amdgcn_exp2f(ev) : 0.0f;
            s2s += pe;
            og = fmaf(pe, wh2[m], og);
        }
        og /= s2s;
        g[n] = (og > 0.0f) ? og : (__expf(og) - 1.0f);     // elu
    }

    // ---- MLP heads ----
    v2f gp[4];
    #pragma unroll
    for (int k = 0; k < 4; ++k) gp[k] = (v2f){g[2 * k], g[2 * k + 1]};

    const v2f* muWp = (const v2f*)muWg;
    const v2f* sgWp = (const v2f*)sgWg;
    const v2f* vWp  = (const v2f*)vWg;

    float mu[8], sg[8];
    #pragma unroll
    for (int j = 0; j < 8; ++j) {
        v2f ma = (v2f){0.0f,0.0f}, sa = (v2f){0.0f,0.0f};
        #pragma unroll
        for (int k = 0; k < 4; ++k) {
            ma = __builtin_elementwise_fma(gp[k], muWp[j * 4 + k], ma);
            sa = __builtin_elementwise_fma(gp[k], sgWp[j * 4 + k], sa);
        }
        float m = ma.x + ma.y + mubg[j];
        float t = sa.x + sa.y + sgbg[j];
        mu[j] = 1.0f / (1.0f + __expf(-m));                            // sigmoid
        sg[j] = fmaxf(t, 0.0f) + log1pf(__expf(-fabsf(t))) + 0.001f;   // softplus
    }
    v2f va = (v2f){0.0f,0.0f};
    #pragma unroll
    for (int k = 0; k < 4; ++k) va = __builtin_elementwise_fma(gp[k], vWp[k], va);
    float vv = va.x + va.y + vbg[0];

    // ---- stores: 2x float4 mu, 2x float4 sigma, 1 float value ----
    float4* om = (float4*)(outg + b * 8);
    om[0] = (float4){mu[0], mu[1], mu[2], mu[3]};
    om[1] = (float4){mu[4], mu[5], mu[6], mu[7]};
    float4* os = (float4*)(outg + (size_t)Bn * 8 + b * 8);
    os[0] = (float4){sg[0], sg[1], sg[2], sg[3]};
    os[1] = (float4){sg[4], sg[5], sg[6], sg[7]};
    outg[(size_t)Bn * 16 + b] = vv;
}

extern "C" void kernel_launch(void* const* d_in, const int* in_sizes, int n_in,
                              void* d_out, int out_size, void* d_ws, size_t ws_size,
                              hipStream_t stream) {
    const float* xg   = (const float*)d_in[0];
    const float* adjg = (const float*)d_in[1];
    const float* Wg   = (const float*)d_in[2];
    const float* ahg  = (const float*)d_in[3];
    const float* wog  = (const float*)d_in[4];
    const float* aog  = (const float*)d_in[5];
    const float* muW  = (const float*)d_in[6];
    const float* mub  = (const float*)d_in[7];
    const float* sgW  = (const float*)d_in[8];
    const float* sgb  = (const float*)d_in[9];
    const float* vW   = (const float*)d_in[10];
    const float* vb   = (const float*)d_in[11];
    float* outg = (float*)d_out;

    dim3 grid(Bn / TPB);   // 512 blocks of 256 threads; 1 graph per thread
    gat_ppo_kernel<<<grid, TPB, 0, stream>>>(xg, adjg, Wg, ahg, wog, aog,
                                             muW, mub, sgW, sgb, vW, vb, outg);
}

// Round 15
// 56.284 us; speedup vs baseline: 2.4192x; 2.4192x over previous
//
#include <hip/hip_runtime.h>
#include <math.h>

#define TPB 256

constexpr int Bn    = 131072;
constexpr float LOG2E = 1.4426950408889634f;

typedef float v2f __attribute__((ext_vector_type(2)));

// ---- DPP helpers: rotation within a 16-lane row (VALU pipe, not LDS) ----
// row_ror:2 = dpp_ctrl 0x122. Direction is made irrelevant by rotating a
// node-id register (mcur) together with the data.
__device__ __forceinline__ float fror2(float v) {
    int i = __builtin_bit_cast(int, v);
    i = __builtin_amdgcn_update_dpp(i, i, 0x122, 0xf, 0xf, false);
    return __builtin_bit_cast(float, i);
}
__device__ __forceinline__ int iror2(int v) {
    return __builtin_amdgcn_update_dpp(v, v, 0x122, 0xf, 0xf, false);
}
__device__ __forceinline__ v2f vror2(v2f v) {
    v2f o; o.x = fror2(v.x); o.y = fror2(v.y); return o;
}

__global__ __launch_bounds__(TPB)
void gat_ppo_kernel(const float* __restrict__ xg,
                    const float* __restrict__ adjg,
                    const float* __restrict__ Wg,
                    const float* __restrict__ ahg,
                    const float* __restrict__ wog,
                    const float* __restrict__ aog,
                    const float* __restrict__ muWg,
                    const float* __restrict__ mubg,
                    const float* __restrict__ sgWg,
                    const float* __restrict__ sgbg,
                    const float* __restrict__ vWg,
                    const float* __restrict__ vbg,
                    float* __restrict__ outg)
{
    // 16-lane row = TWO graphs interleaved: parity = lane&1 picks the graph,
    // node n = (lane&15)>>1. row_ror:2 rotates node-data within each graph
    // (parity preserved). ZERO LDS, zero barriers; only the MLP g-exchange
    // uses 8 bpermutes. Cross-lane attention flow runs on the VALU pipe.
    const int lb   = threadIdx.x;
    const int r16  = lb & 15;
    const int par  = r16 & 1;               // graph parity within row
    const int n    = r16 >> 1;               // node id
    const size_t b = (size_t)blockIdx.x * 32 + (lb >> 4) * 2 + par;  // graph

    // ---- adj row n -> 8-bit mask ----
    unsigned amask;
    {
        const float4* a4 = (const float4*)(adjg + b * 64 + n * 8);
        float4 a0 = a4[0], a1 = a4[1];
        amask =  (unsigned)(a0.x > 0.0f)
              | ((unsigned)(a0.y > 0.0f) << 1)
              | ((unsigned)(a0.z > 0.0f) << 2)
              | ((unsigned)(a0.w > 0.0f) << 3)
              | ((unsigned)(a1.x > 0.0f) << 4)
              | ((unsigned)(a1.y > 0.0f) << 5)
              | ((unsigned)(a1.z > 0.0f) << 6)
              | ((unsigned)(a1.w > 0.0f) << 7);
    }

    // ---- x row (30 floats) ----
    float x[30];
    {
        const float2* xr = (const float2*)(xg + ((size_t)b * 8 + n) * 30);
        #pragma unroll
        for (int k = 0; k < 15; ++k) {
            float2 v = xr[k];
            x[2 * k] = v.x; x[2 * k + 1] = v.y;
        }
    }

    const v2f* Wp = (const v2f*)Wg;
    float wh2 = 0.0f;

    #pragma unroll
    for (int h = 0; h < 3; ++h) {
        // ---- Wh row for own node (pk-FMA, wave-uniform s_load weights) ----
        v2f acc[4];
        #pragma unroll
        for (int o2 = 0; o2 < 4; ++o2) acc[o2] = (v2f){0.0f, 0.0f};
        #pragma unroll
        for (int f = 0; f < 30; ++f) {
            v2f xf = (v2f){x[f], x[f]};
            #pragma unroll
            for (int o2 = 0; o2 < 4; ++o2)
                acc[o2] = __builtin_elementwise_fma(xf, Wp[h * 120 + f * 4 + o2], acc[o2]);
        }

        // ---- scores (log2 domain) ----
        float s1 = 0.0f, s2 = 0.0f;
        #pragma unroll
        for (int o2 = 0; o2 < 4; ++o2) {
            s1 = fmaf(acc[o2].x, ahg[h * 16 + 2 * o2],     s1);
            s1 = fmaf(acc[o2].y, ahg[h * 16 + 2 * o2 + 1], s1);
            s2 = fmaf(acc[o2].x, ahg[h * 16 + 8 + 2 * o2],     s2);
            s2 = fmaf(acc[o2].y, ahg[h * 16 + 8 + 2 * o2 + 1], s2);
        }
        float f1h = s1 * LOG2E;
        float f2h = s2 * LOG2E;

        // ---- rotate-accumulate attention (VALU-pipe DPP, no LDS) ----
        float rf2 = f2h;
        v2f rw0 = acc[0], rw1 = acc[1], rw2 = acc[2], rw3 = acc[3];
        int mcur = n;                         // node id travelling with data
        float ssum = 0.0f;
        v2f hacc0 = (v2f){0.0f,0.0f}, hacc1 = (v2f){0.0f,0.0f};
        v2f hacc2 = (v2f){0.0f,0.0f}, hacc3 = (v2f){0.0f,0.0f};
        #pragma unroll
        for (int step = 0; step < 8; ++step) {
            float ev = f1h + rf2;
            ev = fmaxf(ev, 0.2f * ev);        // leaky (log2-scaled)
            float pe = ((amask >> mcur) & 1u) ? __builtin_amdgcn_exp2f(ev) : 0.0f;
            ssum += pe;
            v2f av = (v2f){pe, pe};
            hacc0 = __builtin_elementwise_fma(av, rw0, hacc0);
            hacc1 = __builtin_elementwise_fma(av, rw1, hacc1);
            hacc2 = __builtin_elementwise_fma(av, rw2, hacc2);
            hacc3 = __builtin_elementwise_fma(av, rw3, hacc3);
            if (step < 7) {
                rf2 = fror2(rf2);
                rw0 = vror2(rw0); rw1 = vror2(rw1);
                rw2 = vror2(rw2); rw3 = vror2(rw3);
                mcur = iror2(mcur);
            }
        }
        float rs = 1.0f / ssum;

        // ---- elu + W_out fold ----
        v2f hh[4] = {hacc0, hacc1, hacc2, hacc3};
        #pragma unroll
        for (int o2 = 0; o2 < 4; ++o2) {
            #pragma unroll
            for (int j = 0; j < 2; ++j) {
                float hv = hh[o2][j] * rs;
                hv = (hv > 0.0f) ? hv : (__expf(hv) - 1.0f);   // elu
                wh2 = fmaf(hv, wog[h * 8 + 2 * o2 + j], wh2);  // h @ W_out
            }
        }
    }

    // ---- second GAT layer via rotation (log2 domain, deferred norm) ----
    const float a0c = aog[0] * LOG2E, a1c = aog[1] * LOG2E;
    {
        float g1 = a0c * wh2;
        float rwh2 = wh2;
        int mc = n;
        float s2s = 0.0f, og = 0.0f;
        #pragma unroll
        for (int step = 0; step < 8; ++step) {
            float ev = fmaf(a1c, rwh2, g1);
            ev = fmaxf(ev, 0.2f * ev);
            float pe = ((amask >> mc) & 1u) ? __builtin_amdgcn_exp2f(ev) : 0.0f;
            s2s += pe;
            og = fmaf(pe, rwh2, og);
            if (step < 7) {
                rwh2 = fror2(rwh2);
                mc = iror2(mc);
            }
        }
        og /= s2s;
        wh2 = (og > 0.0f) ? og : (__expf(og) - 1.0f);      // g[b][n]
    }
    const float g2v = wh2;

    // ---- MLP heads (g-exchange: 8 bpermutes, the only DS ops left) ----
    // g[j] of MY graph lives at lane 2*j + par within the 16-lane row.
    v2f gp[4];
    #pragma unroll
    for (int k = 0; k < 4; ++k)
        gp[k] = (v2f){__shfl(g2v, 4 * k + par,     16),
                      __shfl(g2v, 4 * k + 2 + par, 16)};

    const v2f* muWp = (const v2f*)muWg;
    const v2f* sgWp = (const v2f*)sgWg;
    const v2f* vWp  = (const v2f*)vWg;
    v2f ma = (v2f){0.0f, 0.0f}, sa = (v2f){0.0f, 0.0f}, va = (v2f){0.0f, 0.0f};
    #pragma unroll
    for (int k = 0; k < 4; ++k) {
        ma = __builtin_elementwise_fma(gp[k], muWp[n * 4 + k], ma);
        sa = __builtin_elementwise_fma(gp[k], sgWp[n * 4 + k], sa);
        va = __builtin_elementwise_fma(gp[k], vWp[k],          va);
    }
    float mu = ma.x + ma.y + mubg[n];
    float sg = sa.x + sa.y + sgbg[n];
    float vv = va.x + va.y + vbg[0];

    mu = 1.0f / (1.0f + __expf(-mu));                               // sigmoid
    sg = fmaxf(sg, 0.0f) + log1pf(__expf(-fabsf(sg))) + 0.001f;     // softplus + 1e-3

    outg[b * 8 + n]                    = mu;
    outg[(size_t)Bn * 8 + b * 8 + n]   = sg;
    if (n == 0) outg[(size_t)Bn * 16 + b] = vv;
}

extern "C" void kernel_launch(void* const* d_in, const int* in_sizes, int n_in,
                              void* d_out, int out_size, void* d_ws, size_t ws_size,
                              hipStream_t stream) {
    const float* xg   = (const float*)d_in[0];
    const float* adjg = (const float*)d_in[1];
    const float* Wg   = (const float*)d_in[2];
    const float* ahg  = (const float*)d_in[3];
    const float* wog  = (const float*)d_in[4];
    const float* aog  = (const float*)d_in[5];
    const float* muW  = (const float*)d_in[6];
    const float* mub  = (const float*)d_in[7];
    const float* sgW  = (const float*)d_in[8];
    const float* sgb  = (const float*)d_in[9];
    const float* vW   = (const float*)d_in[10];
    const float* vb   = (const float*)d_in[11];
    float* outg = (float*)d_out;

    dim3 grid(Bn / 32);   // 4096 blocks of 256 threads; 32 graphs per block
    gat_ppo_kernel<<<grid, TPB, 0, stream>>>(xg, adjg, Wg, ahg, wog, aog,
                                             muW, mub, sgW, sgb, vW, vb, outg);
}